// Round 6
// baseline (1028.756 us; speedup 1.0000x reference)
//
#include <hip/hip_runtime.h>

#define NUSERS 250000
#define NITEMS 250000
#define NNODES 500000
#define NEDGES 1200000
#define NBLK   1954          // ceil(NNODES/256)
#define NGROUPS (NNODES/16)  // 31250 16-node groups
#define NGBLK  7813          // ceil(NGROUPS/4)

typedef _Float16 half_t;
typedef _Float16 half8 __attribute__((ext_vector_type(8)));
typedef _Float16 half4 __attribute__((ext_vector_type(4)));
typedef float    f32x4 __attribute__((ext_vector_type(4)));

// ---------------- degree / normalization ----------------

__global__ void k_zero_deg(int* __restrict__ deg) {
    int n = blockIdx.x * blockDim.x + threadIdx.x;
    if (n < NNODES) deg[n] = 0;
}

__global__ void k_count_deg(const int* __restrict__ dst, int* __restrict__ deg) {
    int e = blockIdx.x * blockDim.x + threadIdx.x;
    if (e < NEDGES) atomicAdd(&deg[dst[e]], 1);
}

__global__ void k_dinv(const int* __restrict__ deg, float* __restrict__ dinv) {
    int n = blockIdx.x * blockDim.x + threadIdx.x;
    if (n < NNODES) dinv[n] = 1.0f / sqrtf((float)(deg[n] + 1));
}

// ---------------- CSR build ----------------

__global__ __launch_bounds__(256) void k_block_sums(const int* __restrict__ deg,
                                                    int* __restrict__ partials) {
    __shared__ int sm[256];
    int t = threadIdx.x;
    int n = blockIdx.x * 256 + t;
    int v = (n < NNODES) ? deg[n] : 0;
    sm[t] = v; __syncthreads();
    for (int d = 128; d > 0; d >>= 1) {
        if (t < d) sm[t] += sm[t + d];
        __syncthreads();
    }
    if (t == 0) partials[blockIdx.x] = sm[0];
}

__global__ __launch_bounds__(256) void k_scan_partials(int* __restrict__ partials) {
    __shared__ int sm[256];
    int t = threadIdx.x;
    int v[8]; int s = 0;
#pragma unroll
    for (int i = 0; i < 8; ++i) {
        int idx = t * 8 + i;
        v[i] = (idx < NBLK) ? partials[idx] : 0;
        s += v[i];
    }
    sm[t] = s; __syncthreads();
    for (int d = 1; d < 256; d <<= 1) {
        int x = (t >= d) ? sm[t - d] : 0;
        __syncthreads();
        sm[t] += x;
        __syncthreads();
    }
    int run = sm[t] - s;
#pragma unroll
    for (int i = 0; i < 8; ++i) {
        int idx = t * 8 + i;
        if (idx < NBLK) partials[idx] = run;
        run += v[i];
    }
}

__global__ __launch_bounds__(256) void k_scan_blocks(const int* __restrict__ partials,
                                                     int* __restrict__ degcursor,
                                                     int* __restrict__ offsets) {
    __shared__ int sm[256];
    int t = threadIdx.x;
    int n = blockIdx.x * 256 + t;
    int v = (n < NNODES) ? degcursor[n] : 0;
    sm[t] = v; __syncthreads();
    for (int d = 1; d < 256; d <<= 1) {
        int x = (t >= d) ? sm[t - d] : 0;
        __syncthreads();
        sm[t] += x;
        __syncthreads();
    }
    int off = partials[blockIdx.x] + sm[t] - v;
    if (n < NNODES) {
        offsets[n]   = off;
        degcursor[n] = off;
        if (n == NNODES - 1) offsets[NNODES] = off + v;
    }
}

// pack (src<<4) | (dst & 15): src < 2^19, so 23 bits total
__global__ void k_place(const int* __restrict__ src, const int* __restrict__ dst,
                        int* __restrict__ cursor, int* __restrict__ csr_pk) {
    int e = blockIdx.x * blockDim.x + threadIdx.x;
    if (e < NEDGES) {
        int d = dst[e];
        int pos = atomicAdd(&cursor[d], 1);
        csr_pk[pos] = (src[e] << 4) | (d & 15);
    }
}

// ---------------- MFMA helpers ----------------
// A: lane holds row (lane&15), k = 32q + 8*(lane>>4) + j
// B: lane holds col-slot (lane&15), same k formula; out-feature = 4*(lane&15)+c
// C/D: node = n0 + (lane>>4)*4 + r, feat = 4*(lane&15)+c

__device__ __forceinline__ void build_bfrags(const float* __restrict__ W,
                                             int lg, int cl, half8 bf[2][4]) {
#pragma unroll
    for (int q = 0; q < 2; ++q)
#pragma unroll
        for (int c = 0; c < 4; ++c) {
            half8 v;
#pragma unroll
            for (int j = 0; j < 8; ++j)
                v[j] = (half_t)W[(32 * q + 8 * lg + j) * 64 + 4 * cl + c];
            bf[q][c] = v;
        }
}

// ---------------- k_mm1: g1 = (gather(emb) @ W1) * dinv  [fp16 out] ----------------

__global__ __launch_bounds__(256) void k_mm1(
    const float* __restrict__ user_table, const float* __restrict__ item_table,
    const int* __restrict__ uid, const int* __restrict__ iid,
    const float* __restrict__ W1, const float* __restrict__ dinv,
    half_t* __restrict__ g)
{
    const int lane = threadIdx.x & 63;
    const int lg = lane >> 4, cl = lane & 15;
    const int wid = blockIdx.x * (blockDim.x >> 6) + (threadIdx.x >> 6);
    const int nw  = gridDim.x * (blockDim.x >> 6);

    half8 bf[2][4];
    build_bfrags(W1, lg, cl, bf);
    const f32x4 zacc = {0.f, 0.f, 0.f, 0.f};

    for (int t = wid; t < NNODES / 16; t += nw) {
        const int n0 = t * 16;
        const int na = n0 + cl;                    // NUSERS%16==0: tiles never straddle
        const float* p = (na < NUSERS)
            ? user_table + (size_t)uid[na] * 64
            : item_table + (size_t)iid[na - NUSERS] * 64;
        f32x4 u0 = *(const f32x4*)(p + 8 * lg);
        f32x4 u1 = *(const f32x4*)(p + 8 * lg + 4);
        f32x4 u2 = *(const f32x4*)(p + 8 * lg + 32);
        f32x4 u3 = *(const f32x4*)(p + 8 * lg + 36);
        half8 a0, a1;
#pragma unroll
        for (int j = 0; j < 4; ++j) {
            a0[j] = (half_t)u0[j]; a0[4 + j] = (half_t)u1[j];
            a1[j] = (half_t)u2[j]; a1[4 + j] = (half_t)u3[j];
        }
        f32x4 acc[4];
#pragma unroll
        for (int c = 0; c < 4; ++c) {
            acc[c] = __builtin_amdgcn_mfma_f32_16x16x32_f16(a0, bf[0][c], zacc, 0, 0, 0);
            acc[c] = __builtin_amdgcn_mfma_f32_16x16x32_f16(a1, bf[1][c], acc[c], 0, 0, 0);
        }
#pragma unroll
        for (int r = 0; r < 4; ++r) {
            const int nd = n0 + lg * 4 + r;
            const float dn = dinv[nd];
            half4 hv;
#pragma unroll
            for (int c = 0; c < 4; ++c) hv[c] = (half_t)(acc[c][r] * dn);
            *(half4*)(g + (size_t)nd * 64 + 4 * cl) = hv;
        }
    }
}

// ---------------- LDS exact-edge gather (shared body) ----------------
// wave gw owns nodes [gw*16, gw*16+16); tile[wv][j][lane] accumulates feature
// `lane` of node n0+j in f32. Rows padded to 68 floats.

#define GATHER_BODY(gin)                                                          \
    if (active) {                                                                 \
        _Pragma("unroll")                                                         \
        for (int j = 0; j < 16; ++j)                                              \
            tile[wv][j][lane] = (float)gin[(size_t)(n0 + j) * 64 + lane];         \
        int e  = off[n0];                                                         \
        int en = off[n0 + 16];                                                    \
        for (; e + 8 <= en; e += 8) {                                             \
            int p0 = csr[e],     p1 = csr[e + 1], p2 = csr[e + 2], p3 = csr[e + 3];\
            int p4 = csr[e + 4], p5 = csr[e + 5], p6 = csr[e + 6], p7 = csr[e + 7];\
            float r0 = (float)gin[(size_t)(p0 >> 4) * 64 + lane];                 \
            float r1 = (float)gin[(size_t)(p1 >> 4) * 64 + lane];                 \
            float r2 = (float)gin[(size_t)(p2 >> 4) * 64 + lane];                 \
            float r3 = (float)gin[(size_t)(p3 >> 4) * 64 + lane];                 \
            float r4 = (float)gin[(size_t)(p4 >> 4) * 64 + lane];                 \
            float r5 = (float)gin[(size_t)(p5 >> 4) * 64 + lane];                 \
            float r6 = (float)gin[(size_t)(p6 >> 4) * 64 + lane];                 \
            float r7 = (float)gin[(size_t)(p7 >> 4) * 64 + lane];                 \
            atomicAdd(&tile[wv][p0 & 15][lane], r0);                              \
            atomicAdd(&tile[wv][p1 & 15][lane], r1);                              \
            atomicAdd(&tile[wv][p2 & 15][lane], r2);                              \
            atomicAdd(&tile[wv][p3 & 15][lane], r3);                              \
            atomicAdd(&tile[wv][p4 & 15][lane], r4);                              \
            atomicAdd(&tile[wv][p5 & 15][lane], r5);                              \
            atomicAdd(&tile[wv][p6 & 15][lane], r6);                              \
            atomicAdd(&tile[wv][p7 & 15][lane], r7);                              \
        }                                                                         \
        for (; e < en; ++e) {                                                     \
            int p = csr[e];                                                       \
            atomicAdd(&tile[wv][p & 15][lane],                                    \
                      (float)gin[(size_t)(p >> 4) * 64 + lane]);                  \
        }                                                                         \
    }                                                                             \
    __syncthreads();

// gather(g1) -> relu(dinv*sum+b1) -> @W2 -> *dinv -> g2   [fused layer 2]
__global__ __launch_bounds__(256) void k_gather_mm2(
    const int* __restrict__ off, const int* __restrict__ csr,
    const float* __restrict__ W2, const float* __restrict__ b1,
    const float* __restrict__ dinv,
    const half_t* __restrict__ g1, half_t* __restrict__ g2)
{
    __shared__ float tile[4][16][68];
    const int lane = threadIdx.x & 63;
    const int wv   = threadIdx.x >> 6;
    const int lg = lane >> 4, cl = lane & 15;
    const int gw = blockIdx.x * 4 + wv;
    const bool active = (gw < NGROUPS);
    const int n0 = active ? gw * 16 : 0;

    GATHER_BODY(g1)

    if (!active) return;

    half8 bf[2][4];
    build_bfrags(W2, lg, cl, bf);
    float bias0[8], bias1[8];
#pragma unroll
    for (int j = 0; j < 8; ++j) {
        bias0[j] = b1[8 * lg + j];
        bias1[j] = b1[32 + 8 * lg + j];
    }

    const float dna = dinv[n0 + cl];
    half8 a0, a1;
#pragma unroll
    for (int j = 0; j < 8; ++j) {
        a0[j] = (half_t)fmaxf(fmaf(dna, tile[wv][cl][8 * lg + j],      bias0[j]), 0.0f);
        a1[j] = (half_t)fmaxf(fmaf(dna, tile[wv][cl][32 + 8 * lg + j], bias1[j]), 0.0f);
    }
    const f32x4 zacc = {0.f, 0.f, 0.f, 0.f};
    f32x4 acc[4];
#pragma unroll
    for (int c = 0; c < 4; ++c) {
        acc[c] = __builtin_amdgcn_mfma_f32_16x16x32_f16(a0, bf[0][c], zacc, 0, 0, 0);
        acc[c] = __builtin_amdgcn_mfma_f32_16x16x32_f16(a1, bf[1][c], acc[c], 0, 0, 0);
    }
#pragma unroll
    for (int r = 0; r < 4; ++r) {
        const int nd = n0 + lg * 4 + r;
        const float dn = dinv[nd];
        half4 hv;
#pragma unroll
        for (int c = 0; c < 4; ++c) hv[c] = (half_t)(acc[c][r] * dn);
        *(half4*)(g2 + (size_t)nd * 64 + 4 * cl) = hv;
    }
}

// gather(g2) -> relu(dinv*sum+b2) -> dot(Wp-half) -> pscore   [fused final]
__global__ __launch_bounds__(256) void k_gather_final(
    const int* __restrict__ off, const int* __restrict__ csr,
    const float* __restrict__ b2, const float* __restrict__ Wp,
    const float* __restrict__ dinv,
    const half_t* __restrict__ g2, float* __restrict__ pscore)
{
    __shared__ float tile[4][16][68];
    const int lane = threadIdx.x & 63;
    const int wv   = threadIdx.x >> 6;
    const int gw = blockIdx.x * 4 + wv;
    const bool active = (gw < NGROUPS);
    const int n0 = active ? gw * 16 : 0;

    GATHER_BODY(g2)

    if (!active) return;

    const float bb = b2[lane];
    const float wsel = (n0 < NUSERS) ? Wp[lane] : Wp[64 + lane];  // group uniform
#pragma unroll
    for (int j = 0; j < 16; ++j) {
        float x2 = fmaxf(fmaf(dinv[n0 + j], tile[wv][j][lane], bb), 0.0f);
        float t = x2 * wsel;
#pragma unroll
        for (int o2 = 32; o2 > 0; o2 >>= 1) t += __shfl_xor(t, o2, 64);
        if (lane == 0) pscore[n0 + j] = t;
    }
}

__global__ void k_pairs(const int* __restrict__ user_ids, const int* __restrict__ item_ids,
                        const float* __restrict__ pscore, const float* __restrict__ bp,
                        float* __restrict__ out)
{
    int b = blockIdx.x * blockDim.x + threadIdx.x;
    if (b < NUSERS)
        out[b] = pscore[user_ids[b]] + pscore[NUSERS + item_ids[b]] + bp[0];
}

// ---------------- launch ----------------
// Workspace layout (byte-exact):
//   deg/cursor :          0 ..   2,000,000   (reused as pscore after k_place)
//   dinv       :  2,000,000 ..   4,000,000
//   offsets    :  4,000,000 ..   6,000,004   (NNODES+1 ints)
//   partials   :  6,000,128 ..   6,007,944
//   csr_pk     :  6,008,000 ..  10,808,000
//   bufA (g1)  : 10,808,064 ..  74,808,064   (NNODES*64 fp16)
//   bufB (g2)  : 74,808,064 .. 138,808,064

extern "C" void kernel_launch(void* const* d_in, const int* in_sizes, int n_in,
                              void* d_out, int out_size, void* d_ws, size_t ws_size,
                              hipStream_t stream)
{
    const float* user_table = (const float*)d_in[0];
    const float* item_table = (const float*)d_in[1];
    const float* W1 = (const float*)d_in[2];
    const float* b1 = (const float*)d_in[3];
    const float* W2 = (const float*)d_in[4];
    const float* b2 = (const float*)d_in[5];
    const float* Wp = (const float*)d_in[6];
    const float* bp = (const float*)d_in[7];
    const int* edge = (const int*)d_in[8];
    const int* uid  = (const int*)d_in[9];
    const int* iid  = (const int*)d_in[10];
    float* out = (float*)d_out;

    const int* src = edge;
    const int* dst = edge + NEDGES;

    char* ws = (char*)d_ws;
    int*    deg      = (int*)   (ws + 0);
    float*  dinv     = (float*) (ws + 2000000);
    int*    offsets  = (int*)   (ws + 4000000);
    int*    partials = (int*)   (ws + 6000128);
    int*    csr_pk   = (int*)   (ws + 6008000);
    half_t* bufA     = (half_t*)(ws + 10808064);
    half_t* bufB     = (half_t*)(ws + 74808064);
    float*  pscore   = (float*) (ws + 0);        // aliases deg (dead after k_place)

    k_zero_deg     <<<NBLK, 256, 0, stream>>>(deg);
    k_count_deg    <<<(NEDGES + 255) / 256, 256, 0, stream>>>(dst, deg);
    k_dinv         <<<NBLK, 256, 0, stream>>>(deg, dinv);
    k_block_sums   <<<NBLK, 256, 0, stream>>>(deg, partials);
    k_scan_partials<<<1, 256, 0, stream>>>(partials);
    k_scan_blocks  <<<NBLK, 256, 0, stream>>>(partials, deg, offsets);
    k_place        <<<(NEDGES + 255) / 256, 256, 0, stream>>>(src, dst, deg, csr_pk);

    k_mm1          <<<1024, 256, 0, stream>>>(user_table, item_table, uid, iid, W1, dinv, bufA);
    k_gather_mm2   <<<NGBLK, 256, 0, stream>>>(offsets, csr_pk, W2, b1, dinv, bufA, bufB);
    k_gather_final <<<NGBLK, 256, 0, stream>>>(offsets, csr_pk, b2, Wp, dinv, bufB, pscore);
    k_pairs        <<<(NUSERS + 255) / 256, 256, 0, stream>>>(uid, iid, pscore, bp, out);
}

// Round 7
// 464.023 us; speedup vs baseline: 2.2170x; 2.2170x over previous
//
#include <hip/hip_runtime.h>

#define NUSERS 250000
#define NITEMS 250000
#define NNODES 500000
#define NEDGES 1200000
#define NBLK   1954          // ceil(NNODES/256)
#define NGROUPS (NNODES/16)  // 31250
#define NCHUNKS (NNODES/8)   // 62500

typedef _Float16 half_t;
typedef _Float16 half8 __attribute__((ext_vector_type(8)));
typedef _Float16 half4 __attribute__((ext_vector_type(4)));
typedef float    f32x4 __attribute__((ext_vector_type(4)));

// ---------------- degree / normalization ----------------

__global__ void k_zero_deg(int* __restrict__ deg) {
    int n = blockIdx.x * blockDim.x + threadIdx.x;
    if (n < NNODES) deg[n] = 0;
}

__global__ void k_count_deg(const int* __restrict__ dst, int* __restrict__ deg) {
    int e = blockIdx.x * blockDim.x + threadIdx.x;
    if (e < NEDGES) atomicAdd(&deg[dst[e]], 1);
}

__global__ void k_dinv(const int* __restrict__ deg, float* __restrict__ dinv) {
    int n = blockIdx.x * blockDim.x + threadIdx.x;
    if (n < NNODES) dinv[n] = 1.0f / sqrtf((float)(deg[n] + 1));
}

// ---------------- CSR build ----------------

__global__ __launch_bounds__(256) void k_block_sums(const int* __restrict__ deg,
                                                    int* __restrict__ partials) {
    __shared__ int sm[256];
    int t = threadIdx.x;
    int n = blockIdx.x * 256 + t;
    int v = (n < NNODES) ? deg[n] : 0;
    sm[t] = v; __syncthreads();
    for (int d = 128; d > 0; d >>= 1) {
        if (t < d) sm[t] += sm[t + d];
        __syncthreads();
    }
    if (t == 0) partials[blockIdx.x] = sm[0];
}

__global__ __launch_bounds__(256) void k_scan_partials(int* __restrict__ partials) {
    __shared__ int sm[256];
    int t = threadIdx.x;
    int v[8]; int s = 0;
#pragma unroll
    for (int i = 0; i < 8; ++i) {
        int idx = t * 8 + i;
        v[i] = (idx < NBLK) ? partials[idx] : 0;
        s += v[i];
    }
    sm[t] = s; __syncthreads();
    for (int d = 1; d < 256; d <<= 1) {
        int x = (t >= d) ? sm[t - d] : 0;
        __syncthreads();
        sm[t] += x;
        __syncthreads();
    }
    int run = sm[t] - s;
#pragma unroll
    for (int i = 0; i < 8; ++i) {
        int idx = t * 8 + i;
        if (idx < NBLK) partials[idx] = run;
        run += v[i];
    }
}

__global__ __launch_bounds__(256) void k_scan_blocks(const int* __restrict__ partials,
                                                     int* __restrict__ degcursor,
                                                     int* __restrict__ offsets) {
    __shared__ int sm[256];
    int t = threadIdx.x;
    int n = blockIdx.x * 256 + t;
    int v = (n < NNODES) ? degcursor[n] : 0;
    sm[t] = v; __syncthreads();
    for (int d = 1; d < 256; d <<= 1) {
        int x = (t >= d) ? sm[t - d] : 0;
        __syncthreads();
        sm[t] += x;
        __syncthreads();
    }
    int off = partials[blockIdx.x] + sm[t] - v;
    if (n < NNODES) {
        offsets[n]   = off;
        degcursor[n] = off;
        if (n == NNODES - 1) offsets[NNODES] = off + v;
    }
}

__global__ void k_place(const int* __restrict__ src, const int* __restrict__ dst,
                        int* __restrict__ cursor, int* __restrict__ csr_src) {
    int e = blockIdx.x * blockDim.x + threadIdx.x;
    if (e < NEDGES) {
        int pos = atomicAdd(&cursor[dst[e]], 1);
        csr_src[pos] = src[e];
    }
}

// ---------------- MFMA helpers ----------------
// A: lane holds row (lane&15), k = 32q + 8*(lane>>4) + j
// B: lane holds col-slot (lane&15), same k formula; out-feature = 4*(lane&15)+c
// C/D: node = n0 + (lane>>4)*4 + r, feat = 4*(lane&15)+c

__device__ __forceinline__ void build_bfrags(const float* __restrict__ W,
                                             int lg, int cl, half8 bf[2][4]) {
#pragma unroll
    for (int q = 0; q < 2; ++q)
#pragma unroll
        for (int c = 0; c < 4; ++c) {
            half8 v;
#pragma unroll
            for (int j = 0; j < 8; ++j)
                v[j] = (half_t)W[(32 * q + 8 * lg + j) * 64 + 4 * cl + c];
            bf[q][c] = v;
        }
}

// ---------------- k_mm1: g1 = (gather(emb) @ W1) * dinv  [fp16 out] ----------------

__global__ __launch_bounds__(256) void k_mm1(
    const float* __restrict__ user_table, const float* __restrict__ item_table,
    const int* __restrict__ uid, const int* __restrict__ iid,
    const float* __restrict__ W1, const float* __restrict__ dinv,
    half_t* __restrict__ g)
{
    const int lane = threadIdx.x & 63;
    const int lg = lane >> 4, cl = lane & 15;
    const int wid = blockIdx.x * (blockDim.x >> 6) + (threadIdx.x >> 6);
    const int nw  = gridDim.x * (blockDim.x >> 6);

    half8 bf[2][4];
    build_bfrags(W1, lg, cl, bf);
    const f32x4 zacc = {0.f, 0.f, 0.f, 0.f};

    for (int t = wid; t < NGROUPS; t += nw) {
        const int n0 = t * 16;
        const int na = n0 + cl;                    // NUSERS%16==0: tiles never straddle
        const float* p = (na < NUSERS)
            ? user_table + (size_t)uid[na] * 64
            : item_table + (size_t)iid[na - NUSERS] * 64;
        f32x4 u0 = *(const f32x4*)(p + 8 * lg);
        f32x4 u1 = *(const f32x4*)(p + 8 * lg + 4);
        f32x4 u2 = *(const f32x4*)(p + 8 * lg + 32);
        f32x4 u3 = *(const f32x4*)(p + 8 * lg + 36);
        half8 a0, a1;
#pragma unroll
        for (int j = 0; j < 4; ++j) {
            a0[j] = (half_t)u0[j]; a0[4 + j] = (half_t)u1[j];
            a1[j] = (half_t)u2[j]; a1[4 + j] = (half_t)u3[j];
        }
        f32x4 acc[4];
#pragma unroll
        for (int c = 0; c < 4; ++c) {
            acc[c] = __builtin_amdgcn_mfma_f32_16x16x32_f16(a0, bf[0][c], zacc, 0, 0, 0);
            acc[c] = __builtin_amdgcn_mfma_f32_16x16x32_f16(a1, bf[1][c], acc[c], 0, 0, 0);
        }
#pragma unroll
        for (int r = 0; r < 4; ++r) {
            const int nd = n0 + lg * 4 + r;
            const float dn = dinv[nd];
            half4 hv;
#pragma unroll
            for (int c = 0; c < 4; ++c) hv[c] = (half_t)(acc[c][r] * dn);
            *(half4*)(g + (size_t)nd * 64 + 4 * cl) = hv;
        }
    }
}

// ---------------- register-chain 8-node gather (r5 core) ----------------

__device__ __forceinline__ void gather8(
    const int* __restrict__ off, const int* __restrict__ csr,
    const half_t* __restrict__ gin, int n0, int lane, float sum[8])
{
    int o[8], oe[8];
#pragma unroll
    for (int j = 0; j < 8; ++j) { o[j] = off[n0 + j]; oe[j] = off[n0 + j + 1]; }
#pragma unroll
    for (int j = 0; j < 8; ++j) sum[j] = (float)gin[(size_t)(n0 + j) * 64 + lane];

    bool any = false;
#pragma unroll
    for (int j = 0; j < 8; ++j) any |= (o[j] < oe[j]);
    while (any) {
        bool va[8]; int s[8];
#pragma unroll
        for (int j = 0; j < 8; ++j) {
            va[j] = o[j] < oe[j];
            s[j] = csr[va[j] ? o[j] : 0];          // always issue (safe addr) -> 8 in flight
        }
        float r[8];
#pragma unroll
        for (int j = 0; j < 8; ++j)
            r[j] = (float)gin[(size_t)(va[j] ? s[j] : 0) * 64 + lane];
        any = false;
#pragma unroll
        for (int j = 0; j < 8; ++j) {
            if (va[j]) { sum[j] += r[j]; ++o[j]; }
            any |= (o[j] < oe[j]);
        }
    }
}

// ---------------- gather(g1) + layer2 MFMA fused -> g2 ----------------
// Wave owns 16 nodes: two 8-node register gathers -> plain ds_write tile ->
// read A-frags (relu applied) -> MFMA @W2 -> *dinv -> g2. No atomics, no barrier
// (same-wave LDS ops are in-order).

__global__ __launch_bounds__(256) void k_gather_mm2(
    const int* __restrict__ off, const int* __restrict__ csr,
    const float* __restrict__ W2, const float* __restrict__ b1,
    const float* __restrict__ dinv,
    const half_t* __restrict__ g1, half_t* __restrict__ g2)
{
    __shared__ float tile[4][16][68];
    const int lane = threadIdx.x & 63;
    const int wv   = threadIdx.x >> 6;
    const int lg = lane >> 4, cl = lane & 15;
    const int wid = blockIdx.x * (blockDim.x >> 6) + (threadIdx.x >> 6);
    const int nw  = gridDim.x * (blockDim.x >> 6);
    const f32x4 zacc = {0.f, 0.f, 0.f, 0.f};

    for (int t = wid; t < NGROUPS; t += nw) {
        const int n0 = t * 16;
        float sum[8];
        gather8(off, csr, g1, n0, lane, sum);
#pragma unroll
        for (int j = 0; j < 8; ++j) tile[wv][j][lane] = sum[j];
        gather8(off, csr, g1, n0 + 8, lane, sum);
#pragma unroll
        for (int j = 0; j < 8; ++j) tile[wv][8 + j][lane] = sum[j];

        // built after gather: short live range keeps gather-phase VGPRs low
        half8 bf[2][4];
        build_bfrags(W2, lg, cl, bf);

        const float dna = dinv[n0 + cl];
        half8 a0, a1;
#pragma unroll
        for (int j = 0; j < 8; ++j) {
            a0[j] = (half_t)fmaxf(fmaf(dna, tile[wv][cl][8 * lg + j],      b1[8 * lg + j]), 0.0f);
            a1[j] = (half_t)fmaxf(fmaf(dna, tile[wv][cl][32 + 8 * lg + j], b1[32 + 8 * lg + j]), 0.0f);
        }
        f32x4 acc[4];
#pragma unroll
        for (int c = 0; c < 4; ++c) {
            acc[c] = __builtin_amdgcn_mfma_f32_16x16x32_f16(a0, bf[0][c], zacc, 0, 0, 0);
            acc[c] = __builtin_amdgcn_mfma_f32_16x16x32_f16(a1, bf[1][c], acc[c], 0, 0, 0);
        }
#pragma unroll
        for (int r = 0; r < 4; ++r) {
            const int nd = n0 + lg * 4 + r;
            const float dn = dinv[nd];
            half4 hv;
#pragma unroll
            for (int c = 0; c < 4; ++c) hv[c] = (half_t)(acc[c][r] * dn);
            *(half4*)(g2 + (size_t)nd * 64 + 4 * cl) = hv;
        }
    }
}

// ---------------- gather(g2) + relu + Wp-dot fused -> pscore ----------------

__global__ __launch_bounds__(256) void k_gather_ps(
    const int* __restrict__ off, const int* __restrict__ csr,
    const float* __restrict__ b2, const float* __restrict__ Wp,
    const float* __restrict__ dinv,
    const half_t* __restrict__ g2, float* __restrict__ pscore)
{
    const int lane = threadIdx.x & 63;
    const int wid = blockIdx.x * (blockDim.x >> 6) + (threadIdx.x >> 6);
    const int nw  = gridDim.x * (blockDim.x >> 6);
    const float bb  = b2[lane];
    const float wpu = Wp[lane];
    const float wpi = Wp[64 + lane];

    for (int t = wid; t < NCHUNKS; t += nw) {
        const int n0 = t * 8;
        float sum[8];
        gather8(off, csr, g2, n0, lane, sum);

        const float wsel = (n0 < NUSERS) ? wpu : wpi;   // NUSERS%8==0: chunk uniform
#pragma unroll
        for (int j = 0; j < 8; ++j) {
            float x2 = fmaxf(fmaf(dinv[n0 + j], sum[j], bb), 0.0f);
            float v = x2 * wsel;
#pragma unroll
            for (int o2 = 32; o2 > 0; o2 >>= 1) v += __shfl_xor(v, o2, 64);
            if (lane == 0) pscore[n0 + j] = v;
        }
    }
}

__global__ void k_pairs(const int* __restrict__ user_ids, const int* __restrict__ item_ids,
                        const float* __restrict__ pscore, const float* __restrict__ bp,
                        float* __restrict__ out)
{
    int b = blockIdx.x * blockDim.x + threadIdx.x;
    if (b < NUSERS)
        out[b] = pscore[user_ids[b]] + pscore[NUSERS + item_ids[b]] + bp[0];
}

// ---------------- launch ----------------
// Workspace layout (byte-exact):
//   deg/cursor :          0 ..   2,000,000   (reused as pscore after k_place)
//   dinv       :  2,000,000 ..   4,000,000
//   offsets    :  4,000,000 ..   6,000,004   (NNODES+1 ints)
//   partials   :  6,000,128 ..   6,007,944
//   csr_src    :  6,008,000 ..  10,808,000
//   bufA (g1)  : 10,808,064 ..  74,808,064   (NNODES*64 fp16)
//   bufB (g2)  : 74,808,064 .. 138,808,064

extern "C" void kernel_launch(void* const* d_in, const int* in_sizes, int n_in,
                              void* d_out, int out_size, void* d_ws, size_t ws_size,
                              hipStream_t stream)
{
    const float* user_table = (const float*)d_in[0];
    const float* item_table = (const float*)d_in[1];
    const float* W1 = (const float*)d_in[2];
    const float* b1 = (const float*)d_in[3];
    const float* W2 = (const float*)d_in[4];
    const float* b2 = (const float*)d_in[5];
    const float* Wp = (const float*)d_in[6];
    const float* bp = (const float*)d_in[7];
    const int* edge = (const int*)d_in[8];
    const int* uid  = (const int*)d_in[9];
    const int* iid  = (const int*)d_in[10];
    float* out = (float*)d_out;

    const int* src = edge;
    const int* dst = edge + NEDGES;

    char* ws = (char*)d_ws;
    int*    deg      = (int*)   (ws + 0);
    float*  dinv     = (float*) (ws + 2000000);
    int*    offsets  = (int*)   (ws + 4000000);
    int*    partials = (int*)   (ws + 6000128);
    int*    csr_src  = (int*)   (ws + 6008000);
    half_t* bufA     = (half_t*)(ws + 10808064);
    half_t* bufB     = (half_t*)(ws + 74808064);
    float*  pscore   = (float*) (ws + 0);        // aliases deg (dead after k_place)

    k_zero_deg     <<<NBLK, 256, 0, stream>>>(deg);
    k_count_deg    <<<(NEDGES + 255) / 256, 256, 0, stream>>>(dst, deg);
    k_dinv         <<<NBLK, 256, 0, stream>>>(deg, dinv);
    k_block_sums   <<<NBLK, 256, 0, stream>>>(deg, partials);
    k_scan_partials<<<1, 256, 0, stream>>>(partials);
    k_scan_blocks  <<<NBLK, 256, 0, stream>>>(partials, deg, offsets);
    k_place        <<<(NEDGES + 255) / 256, 256, 0, stream>>>(src, dst, deg, csr_src);

    k_mm1       <<<2048, 256, 0, stream>>>(user_table, item_table, uid, iid, W1, dinv, bufA);
    k_gather_mm2<<<2048, 256, 0, stream>>>(offsets, csr_src, W2, b1, dinv, bufA, bufB);
    k_gather_ps <<<2048, 256, 0, stream>>>(offsets, csr_src, b2, Wp, dinv, bufB, pscore);
    k_pairs     <<<(NUSERS + 255) / 256, 256, 0, stream>>>(uid, iid, pscore, bp, out);
}

// Round 8
// 431.215 us; speedup vs baseline: 2.3857x; 1.0761x over previous
//
#include <hip/hip_runtime.h>

#define NUSERS 250000
#define NITEMS 250000
#define NNODES 500000
#define NEDGES 1200000
#define NBLK   1954          // ceil(NNODES/256)
#define NGROUPS (NNODES/16)  // 31250
#define NCHUNKS (NNODES/8)   // 62500

typedef _Float16 half_t;
typedef _Float16 half8 __attribute__((ext_vector_type(8)));
typedef _Float16 half4 __attribute__((ext_vector_type(4)));
typedef float    f32x4 __attribute__((ext_vector_type(4)));

// ---------------- degree / normalization ----------------

__global__ void k_zero_deg(int* __restrict__ deg) {
    int n = blockIdx.x * blockDim.x + threadIdx.x;
    if (n < NNODES) deg[n] = 0;
}

__global__ void k_count_deg(const int* __restrict__ dst, int* __restrict__ deg) {
    int e = blockIdx.x * blockDim.x + threadIdx.x;
    if (e < NEDGES) atomicAdd(&deg[dst[e]], 1);
}

__global__ void k_dinv(const int* __restrict__ deg, float* __restrict__ dinv) {
    int n = blockIdx.x * blockDim.x + threadIdx.x;
    if (n < NNODES) dinv[n] = 1.0f / sqrtf((float)(deg[n] + 1));
}

// ---------------- CSR build ----------------

__global__ __launch_bounds__(256) void k_block_sums(const int* __restrict__ deg,
                                                    int* __restrict__ partials) {
    __shared__ int sm[256];
    int t = threadIdx.x;
    int n = blockIdx.x * 256 + t;
    int v = (n < NNODES) ? deg[n] : 0;
    sm[t] = v; __syncthreads();
    for (int d = 128; d > 0; d >>= 1) {
        if (t < d) sm[t] += sm[t + d];
        __syncthreads();
    }
    if (t == 0) partials[blockIdx.x] = sm[0];
}

__global__ __launch_bounds__(256) void k_scan_partials(int* __restrict__ partials) {
    __shared__ int sm[256];
    int t = threadIdx.x;
    int v[8]; int s = 0;
#pragma unroll
    for (int i = 0; i < 8; ++i) {
        int idx = t * 8 + i;
        v[i] = (idx < NBLK) ? partials[idx] : 0;
        s += v[i];
    }
    sm[t] = s; __syncthreads();
    for (int d = 1; d < 256; d <<= 1) {
        int x = (t >= d) ? sm[t - d] : 0;
        __syncthreads();
        sm[t] += x;
        __syncthreads();
    }
    int run = sm[t] - s;
#pragma unroll
    for (int i = 0; i < 8; ++i) {
        int idx = t * 8 + i;
        if (idx < NBLK) partials[idx] = run;
        run += v[i];
    }
}

__global__ __launch_bounds__(256) void k_scan_blocks(const int* __restrict__ partials,
                                                     int* __restrict__ degcursor,
                                                     int* __restrict__ offsets) {
    __shared__ int sm[256];
    int t = threadIdx.x;
    int n = blockIdx.x * 256 + t;
    int v = (n < NNODES) ? degcursor[n] : 0;
    sm[t] = v; __syncthreads();
    for (int d = 1; d < 256; d <<= 1) {
        int x = (t >= d) ? sm[t - d] : 0;
        __syncthreads();
        sm[t] += x;
        __syncthreads();
    }
    int off = partials[blockIdx.x] + sm[t] - v;
    if (n < NNODES) {
        offsets[n]   = off;
        degcursor[n] = off;
        if (n == NNODES - 1) offsets[NNODES] = off + v;
    }
}

// pack (src<<3) | (dst&7): src < 2^19 -> fits in 22 bits
__global__ void k_place(const int* __restrict__ src, const int* __restrict__ dst,
                        int* __restrict__ cursor, int* __restrict__ csr_pk) {
    int e = blockIdx.x * blockDim.x + threadIdx.x;
    if (e < NEDGES) {
        int d = dst[e];
        int pos = atomicAdd(&cursor[d], 1);
        csr_pk[pos] = (src[e] << 3) | (d & 7);
    }
}

// ---------------- MFMA helpers ----------------
// A: lane holds row (lane&15), k = 32q + 8*(lane>>4) + j
// B: lane holds col-slot (lane&15), same k formula; out-feature = 4*(lane&15)+c
// C/D: node = n0 + (lane>>4)*4 + r, feat = 4*(lane&15)+c

__device__ __forceinline__ void build_bfrags(const float* __restrict__ W,
                                             int lg, int cl, half8 bf[2][4]) {
#pragma unroll
    for (int q = 0; q < 2; ++q)
#pragma unroll
        for (int c = 0; c < 4; ++c) {
            half8 v;
#pragma unroll
            for (int j = 0; j < 8; ++j)
                v[j] = (half_t)W[(32 * q + 8 * lg + j) * 64 + 4 * cl + c];
            bf[q][c] = v;
        }
}

// ---------------- k_mm1: g1 = (gather(emb) @ W1) * dinv  [fp16 out] ----------------

__global__ __launch_bounds__(256) void k_mm1(
    const float* __restrict__ user_table, const float* __restrict__ item_table,
    const int* __restrict__ uid, const int* __restrict__ iid,
    const float* __restrict__ W1, const float* __restrict__ dinv,
    half_t* __restrict__ g)
{
    const int lane = threadIdx.x & 63;
    const int lg = lane >> 4, cl = lane & 15;
    const int wid = blockIdx.x * (blockDim.x >> 6) + (threadIdx.x >> 6);
    const int nw  = gridDim.x * (blockDim.x >> 6);

    half8 bf[2][4];
    build_bfrags(W1, lg, cl, bf);
    const f32x4 zacc = {0.f, 0.f, 0.f, 0.f};

    for (int t = wid; t < NGROUPS; t += nw) {
        const int n0 = t * 16;
        const int na = n0 + cl;                    // NUSERS%16==0: tiles never straddle
        const float* p = (na < NUSERS)
            ? user_table + (size_t)uid[na] * 64
            : item_table + (size_t)iid[na - NUSERS] * 64;
        f32x4 u0 = *(const f32x4*)(p + 8 * lg);
        f32x4 u1 = *(const f32x4*)(p + 8 * lg + 4);
        f32x4 u2 = *(const f32x4*)(p + 8 * lg + 32);
        f32x4 u3 = *(const f32x4*)(p + 8 * lg + 36);
        half8 a0, a1;
#pragma unroll
        for (int j = 0; j < 4; ++j) {
            a0[j] = (half_t)u0[j]; a0[4 + j] = (half_t)u1[j];
            a1[j] = (half_t)u2[j]; a1[4 + j] = (half_t)u3[j];
        }
        f32x4 acc[4];
#pragma unroll
        for (int c = 0; c < 4; ++c) {
            acc[c] = __builtin_amdgcn_mfma_f32_16x16x32_f16(a0, bf[0][c], zacc, 0, 0, 0);
            acc[c] = __builtin_amdgcn_mfma_f32_16x16x32_f16(a1, bf[1][c], acc[c], 0, 0, 0);
        }
#pragma unroll
        for (int r = 0; r < 4; ++r) {
            const int nd = n0 + lg * 4 + r;
            const float dn = dinv[nd];
            half4 hv;
#pragma unroll
            for (int c = 0; c < 4; ++c) hv[c] = (half_t)(acc[c][r] * dn);
            *(half4*)(g + (size_t)nd * 64 + 4 * cl) = hv;
        }
    }
}

// ---------------- flat exact-edge 8-node gather ----------------
// Chunk of 8 nodes owns contiguous CSR range off[n0]..off[n0+8].
// Batch 8 edges: 8 csr loads + 8 row loads in flight; route rows into sum[j]
// with cndmask-adds (j = packed dst&7, wave-uniform).

__device__ __forceinline__ void gather_flat8(
    const int* __restrict__ off, const int* __restrict__ csr,
    const half_t* __restrict__ gin, int n0, int lane, float sum[8])
{
#pragma unroll
    for (int j = 0; j < 8; ++j)
        sum[j] = (float)gin[(size_t)(n0 + j) * 64 + lane];   // self-loop

    int e  = off[n0];
    const int en = off[n0 + 8];

    for (; e + 8 <= en; e += 8) {
        int p0 = csr[e],     p1 = csr[e + 1], p2 = csr[e + 2], p3 = csr[e + 3];
        int p4 = csr[e + 4], p5 = csr[e + 5], p6 = csr[e + 6], p7 = csr[e + 7];
        float r0 = (float)gin[(size_t)(p0 >> 3) * 64 + lane];
        float r1 = (float)gin[(size_t)(p1 >> 3) * 64 + lane];
        float r2 = (float)gin[(size_t)(p2 >> 3) * 64 + lane];
        float r3 = (float)gin[(size_t)(p3 >> 3) * 64 + lane];
        float r4 = (float)gin[(size_t)(p4 >> 3) * 64 + lane];
        float r5 = (float)gin[(size_t)(p5 >> 3) * 64 + lane];
        float r6 = (float)gin[(size_t)(p6 >> 3) * 64 + lane];
        float r7 = (float)gin[(size_t)(p7 >> 3) * 64 + lane];
        const int j0 = p0 & 7, j1 = p1 & 7, j2 = p2 & 7, j3 = p3 & 7;
        const int j4 = p4 & 7, j5 = p5 & 7, j6 = p6 & 7, j7 = p7 & 7;
#pragma unroll
        for (int k = 0; k < 8; ++k) {
            float a = ((j0 == k) ? r0 : 0.0f) + ((j1 == k) ? r1 : 0.0f)
                    + ((j2 == k) ? r2 : 0.0f) + ((j3 == k) ? r3 : 0.0f);
            float b = ((j4 == k) ? r4 : 0.0f) + ((j5 == k) ? r5 : 0.0f)
                    + ((j6 == k) ? r6 : 0.0f) + ((j7 == k) ? r7 : 0.0f);
            sum[k] += a + b;
        }
    }
    for (; e < en; ++e) {
        int p = csr[e];
        float r = (float)gin[(size_t)(p >> 3) * 64 + lane];
        const int j = p & 7;
#pragma unroll
        for (int k = 0; k < 8; ++k)
            sum[k] += (j == k) ? r : 0.0f;
    }
}

// pure gather: s[n] = g[n] + sum_in g[src]   [fp16 out]
__global__ __launch_bounds__(256) void k_gather(
    const int* __restrict__ off, const int* __restrict__ csr,
    const half_t* __restrict__ gin, half_t* __restrict__ sout)
{
    const int lane = threadIdx.x & 63;
    const int wid = blockIdx.x * (blockDim.x >> 6) + (threadIdx.x >> 6);
    const int nw  = gridDim.x * (blockDim.x >> 6);

    for (int t = wid; t < NCHUNKS; t += nw) {
        const int n0 = t * 8;
        float sum[8];
        gather_flat8(off, csr, gin, n0, lane, sum);
#pragma unroll
        for (int j = 0; j < 8; ++j)
            sout[(size_t)(n0 + j) * 64 + lane] = (half_t)sum[j];
    }
}

// ---------------- k_mm2: g2 = (relu(dinv*s + b1) @ W2) * dinv ----------------

__global__ __launch_bounds__(256) void k_mm2(
    const float* __restrict__ W2, const float* __restrict__ b1,
    const float* __restrict__ dinv,
    const half_t* __restrict__ s, half_t* __restrict__ g)
{
    const int lane = threadIdx.x & 63;
    const int lg = lane >> 4, cl = lane & 15;
    const int wid = blockIdx.x * (blockDim.x >> 6) + (threadIdx.x >> 6);
    const int nw  = gridDim.x * (blockDim.x >> 6);

    half8 bf[2][4];
    build_bfrags(W2, lg, cl, bf);
    float bias0[8], bias1[8];
#pragma unroll
    for (int j = 0; j < 8; ++j) {
        bias0[j] = b1[8 * lg + j];
        bias1[j] = b1[32 + 8 * lg + j];
    }
    const f32x4 zacc = {0.f, 0.f, 0.f, 0.f};

    for (int t = wid; t < NGROUPS; t += nw) {
        const int n0 = t * 16;
        const int na = n0 + cl;
        const float dna = dinv[na];
        half8 s0 = *(const half8*)(s + (size_t)na * 64 + 8 * lg);
        half8 s1 = *(const half8*)(s + (size_t)na * 64 + 32 + 8 * lg);
        half8 a0, a1;
#pragma unroll
        for (int j = 0; j < 8; ++j) {
            a0[j] = (half_t)fmaxf(fmaf(dna, (float)s0[j], bias0[j]), 0.0f);
            a1[j] = (half_t)fmaxf(fmaf(dna, (float)s1[j], bias1[j]), 0.0f);
        }
        f32x4 acc[4];
#pragma unroll
        for (int c = 0; c < 4; ++c) {
            acc[c] = __builtin_amdgcn_mfma_f32_16x16x32_f16(a0, bf[0][c], zacc, 0, 0, 0);
            acc[c] = __builtin_amdgcn_mfma_f32_16x16x32_f16(a1, bf[1][c], acc[c], 0, 0, 0);
        }
#pragma unroll
        for (int r = 0; r < 4; ++r) {
            const int nd = n0 + lg * 4 + r;
            const float dn = dinv[nd];
            half4 hv;
#pragma unroll
            for (int c = 0; c < 4; ++c) hv[c] = (half_t)(acc[c][r] * dn);
            *(half4*)(g + (size_t)nd * 64 + 4 * cl) = hv;
        }
    }
}

// ---------------- gather(g2) + relu + Wp-dot fused -> pscore ----------------

__global__ __launch_bounds__(256) void k_gather_ps(
    const int* __restrict__ off, const int* __restrict__ csr,
    const float* __restrict__ b2, const float* __restrict__ Wp,
    const float* __restrict__ dinv,
    const half_t* __restrict__ g2, float* __restrict__ pscore)
{
    const int lane = threadIdx.x & 63;
    const int wid = blockIdx.x * (blockDim.x >> 6) + (threadIdx.x >> 6);
    const int nw  = gridDim.x * (blockDim.x >> 6);
    const float bb  = b2[lane];
    const float wpu = Wp[lane];
    const float wpi = Wp[64 + lane];

    for (int t = wid; t < NCHUNKS; t += nw) {
        const int n0 = t * 8;
        float sum[8];
        gather_flat8(off, csr, g2, n0, lane, sum);

        const float wsel = (n0 < NUSERS) ? wpu : wpi;   // NUSERS%8==0: chunk uniform
#pragma unroll
        for (int j = 0; j < 8; ++j) {
            float x2 = fmaxf(fmaf(dinv[n0 + j], sum[j], bb), 0.0f);
            float v = x2 * wsel;
#pragma unroll
            for (int o2 = 32; o2 > 0; o2 >>= 1) v += __shfl_xor(v, o2, 64);
            if (lane == 0) pscore[n0 + j] = v;
        }
    }
}

__global__ void k_pairs(const int* __restrict__ user_ids, const int* __restrict__ item_ids,
                        const float* __restrict__ pscore, const float* __restrict__ bp,
                        float* __restrict__ out)
{
    int b = blockIdx.x * blockDim.x + threadIdx.x;
    if (b < NUSERS)
        out[b] = pscore[user_ids[b]] + pscore[NUSERS + item_ids[b]] + bp[0];
}

// ---------------- launch ----------------
// Workspace layout (byte-exact):
//   deg/cursor :          0 ..   2,000,000   (reused as pscore after k_place)
//   dinv       :  2,000,000 ..   4,000,000
//   offsets    :  4,000,000 ..   6,000,004   (NNODES+1 ints)
//   partials   :  6,000,128 ..   6,007,944
//   csr_pk     :  6,008,000 ..  10,808,000
//   bufA       : 10,808,064 ..  74,808,064   (NNODES*64 fp16)  g1, then g2
//   bufB       : 74,808,064 .. 138,808,064   s1

extern "C" void kernel_launch(void* const* d_in, const int* in_sizes, int n_in,
                              void* d_out, int out_size, void* d_ws, size_t ws_size,
                              hipStream_t stream)
{
    const float* user_table = (const float*)d_in[0];
    const float* item_table = (const float*)d_in[1];
    const float* W1 = (const float*)d_in[2];
    const float* b1 = (const float*)d_in[3];
    const float* W2 = (const float*)d_in[4];
    const float* b2 = (const float*)d_in[5];
    const float* Wp = (const float*)d_in[6];
    const float* bp = (const float*)d_in[7];
    const int* edge = (const int*)d_in[8];
    const int* uid  = (const int*)d_in[9];
    const int* iid  = (const int*)d_in[10];
    float* out = (float*)d_out;

    const int* src = edge;
    const int* dst = edge + NEDGES;

    char* ws = (char*)d_ws;
    int*    deg      = (int*)   (ws + 0);
    float*  dinv     = (float*) (ws + 2000000);
    int*    offsets  = (int*)   (ws + 4000000);
    int*    partials = (int*)   (ws + 6000128);
    int*    csr_pk   = (int*)   (ws + 6008000);
    half_t* bufA     = (half_t*)(ws + 10808064);
    half_t* bufB     = (half_t*)(ws + 74808064);
    float*  pscore   = (float*) (ws + 0);        // aliases deg (dead after k_place)

    k_zero_deg     <<<NBLK, 256, 0, stream>>>(deg);
    k_count_deg    <<<(NEDGES + 255) / 256, 256, 0, stream>>>(dst, deg);
    k_dinv         <<<NBLK, 256, 0, stream>>>(deg, dinv);
    k_block_sums   <<<NBLK, 256, 0, stream>>>(deg, partials);
    k_scan_partials<<<1, 256, 0, stream>>>(partials);
    k_scan_blocks  <<<NBLK, 256, 0, stream>>>(partials, deg, offsets);
    k_place        <<<(NEDGES + 255) / 256, 256, 0, stream>>>(src, dst, deg, csr_pk);

    k_mm1      <<<2048, 256, 0, stream>>>(user_table, item_table, uid, iid, W1, dinv, bufA);
    k_gather   <<<2048, 256, 0, stream>>>(offsets, csr_pk, bufA, bufB);
    k_mm2      <<<2048, 256, 0, stream>>>(W2, b1, dinv, bufB, bufA);
    k_gather_ps<<<2048, 256, 0, stream>>>(offsets, csr_pk, b2, Wp, dinv, bufA, pscore);
    k_pairs    <<<(NUSERS + 255) / 256, 256, 0, stream>>>(uid, iid, pscore, bp, out);
}